// Round 1
// baseline (154.485 us; speedup 1.0000x reference)
//
#include <hip/hip_runtime.h>
#include <hip/hip_bf16.h>

// GATConv on MI355X.
// Pipeline:
//   K1: x_l = bf16( x @ W + b )             -> xlb [4096][512] bf16 (MFMA GEMM)
//   K2: transpose xlb -> xlT [512][4096] bf16; alpha_l/r = <x_l, att_l/r> per head
//   K3: per i-tile (32 rows) x j-split: P[i,j,h] = adj ? exp(al[i,h]*ar[j,h]) : 0
//       (no max-subtraction needed: |score| << 87, exp-no-max == exact softmax)
//       acc += P @ x_l (MFMA, P built directly in A-frag layout, no LDS),
//       Z += row-sums of P. Partials to workspace.
//   K4: out = relu( (sum_s acc_s) / (sum_s Z_s) )

#define NN    4096
#define NF    512
#define NH    8
#define CC    64
#define HC    512   // NH*CC
#define SPLITS 2
#define TI    32

typedef __bf16 bf16x8 __attribute__((ext_vector_type(8)));
typedef __bf16 bf16x4 __attribute__((ext_vector_type(4)));
typedef float  f32x4  __attribute__((ext_vector_type(4)));
typedef int    i32x4  __attribute__((ext_vector_type(4)));

// ---------------- K1: projection GEMM (bf16 MFMA, fp32 inputs) ----------------
__global__ __launch_bounds__(256) void k1_gemm(
    const float* __restrict__ X, const float* __restrict__ W,
    const float* __restrict__ bias, __bf16* __restrict__ xlb)
{
    __shared__ __bf16 As[64][40];    // padded stride: 80B, 16B-aligned rows
    __shared__ __bf16 BsT[64][40];   // B stored transposed: [col][k]

    const int tid = threadIdx.x;
    const int w  = tid >> 6;
    const int l  = tid & 63;
    const int lo = l & 15;
    const int hi = l >> 4;
    const int r0 = blockIdx.x * 64;
    const int c0 = blockIdx.y * 64;
    const int wm = (w >> 1) * 32;
    const int wn = (w & 1) * 32;

    f32x4 acc[2][2];
#pragma unroll
    for (int m = 0; m < 2; ++m)
#pragma unroll
        for (int n = 0; n < 2; ++n) acc[m][n] = (f32x4){0.f, 0.f, 0.f, 0.f};

    const int arow = tid >> 3;        // 0..31
    const int acol = (tid & 7) * 4;   // 0..28
    const int brow = tid >> 4;        // 0..15
    const int bcol = (tid & 15) * 4;  // 0..60

    for (int k0 = 0; k0 < NF; k0 += 32) {
        __syncthreads();  // protect LDS from previous iteration's readers
#pragma unroll
        for (int p = 0; p < 2; ++p) {
            int r = arow + p * 32;
            float4 v = *reinterpret_cast<const float4*>(&X[(r0 + r) * NF + k0 + acol]);
            bf16x4 av;
            av[0] = (__bf16)v.x; av[1] = (__bf16)v.y; av[2] = (__bf16)v.z; av[3] = (__bf16)v.w;
            *reinterpret_cast<bf16x4*>(&As[r][acol]) = av;
        }
#pragma unroll
        for (int p = 0; p < 2; ++p) {
            int kk = brow + p * 16;
            float4 v = *reinterpret_cast<const float4*>(&W[(k0 + kk) * HC + c0 + bcol]);
            BsT[bcol + 0][kk] = (__bf16)v.x;
            BsT[bcol + 1][kk] = (__bf16)v.y;
            BsT[bcol + 2][kk] = (__bf16)v.z;
            BsT[bcol + 3][kk] = (__bf16)v.w;
        }
        __syncthreads();

        bf16x8 a[2], b[2];
#pragma unroll
        for (int m = 0; m < 2; ++m)
            a[m] = *reinterpret_cast<const bf16x8*>(&As[wm + m * 16 + lo][hi * 8]);
#pragma unroll
        for (int n = 0; n < 2; ++n)
            b[n] = *reinterpret_cast<const bf16x8*>(&BsT[wn + n * 16 + lo][hi * 8]);
#pragma unroll
        for (int m = 0; m < 2; ++m)
#pragma unroll
            for (int n = 0; n < 2; ++n)
                acc[m][n] = __builtin_amdgcn_mfma_f32_16x16x32_bf16(a[m], b[n], acc[m][n], 0, 0, 0);
    }

#pragma unroll
    for (int m = 0; m < 2; ++m)
#pragma unroll
        for (int n = 0; n < 2; ++n) {
            int col = c0 + wn + n * 16 + lo;
            float bv = bias[col];
#pragma unroll
            for (int r = 0; r < 4; ++r) {
                int row = r0 + wm + m * 16 + hi * 4 + r;
                xlb[row * HC + col] = (__bf16)(acc[m][n][r] + bv);
            }
        }
}

// ---------------- K2: transpose + alpha ----------------
__global__ __launch_bounds__(256) void k2_transpose_alpha(
    const __bf16* __restrict__ xlb, const float* __restrict__ attl,
    const float* __restrict__ attr, __bf16* __restrict__ xlT,
    float* __restrict__ alT, float* __restrict__ arT)
{
    __shared__ __bf16 T[64][72];  // pad 8 -> row stride 144B (16B-aligned)

    const int tid = threadIdx.x;
    const int r0 = blockIdx.x * 64;
    const int h  = blockIdx.y;
    const int c0 = h * CC;

    const int rr_  = tid >> 3;
    const int col8 = (tid & 7) * 8;

    float attl8[8], attr8[8];
#pragma unroll
    for (int j = 0; j < 8; ++j) { attl8[j] = attl[c0 + col8 + j]; attr8[j] = attr[c0 + col8 + j]; }

#pragma unroll
    for (int p = 0; p < 2; ++p) {
        int rr = rr_ + p * 32;
        bf16x8 v = *reinterpret_cast<const bf16x8*>(&xlb[(r0 + rr) * HC + c0 + col8]);
        *reinterpret_cast<bf16x8*>(&T[rr][col8]) = v;
        float pl = 0.f, pr = 0.f;
#pragma unroll
        for (int j = 0; j < 8; ++j) { float f = (float)v[j]; pl += f * attl8[j]; pr += f * attr8[j]; }
        pl += __shfl_xor(pl, 1); pl += __shfl_xor(pl, 2); pl += __shfl_xor(pl, 4);
        pr += __shfl_xor(pr, 1); pr += __shfl_xor(pr, 2); pr += __shfl_xor(pr, 4);
        if ((tid & 7) == 0) { alT[h * NN + r0 + rr] = pl; arT[h * NN + r0 + rr] = pr; }
    }
    __syncthreads();

    const int cc_  = tid >> 3;
    const int row8 = (tid & 7) * 8;
#pragma unroll
    for (int p = 0; p < 2; ++p) {
        int cc = cc_ + p * 32;
        bf16x8 g;
#pragma unroll
        for (int j = 0; j < 8; ++j) g[j] = T[row8 + j][cc];
        *reinterpret_cast<bf16x8*>(&xlT[(c0 + cc) * NN + r0 + row8]) = g;
    }
}

// ---------------- K3: fused mask+exp+aggregate+Z ----------------
__global__ __launch_bounds__(512) void k3_attn(
    const int* __restrict__ adj, const __bf16* __restrict__ xlT,
    const float* __restrict__ alT, const float* __restrict__ arT,
    float* __restrict__ Pacc, float* __restrict__ Zp)
{
    const int tid = threadIdx.x;
    const int h   = tid >> 6;        // wave = head
    const int l   = tid & 63;
    const int lo  = l & 15;
    const int hi  = l >> 4;
    const int nit = NN / TI;         // 128
    const int it  = blockIdx.x % nit;
    const int sp  = blockIdx.x / nit;
    const int i0  = it * TI;
    const int jbeg = sp * (NN / SPLITS);
    const int jend = jbeg + (NN / SPLITS);

    const float al0 = alT[h * NN + i0 + lo];
    const float al1 = alT[h * NN + i0 + 16 + lo];

    f32x4 acc[2][4];
#pragma unroll
    for (int m = 0; m < 2; ++m)
#pragma unroll
        for (int n = 0; n < 4; ++n) acc[m][n] = (f32x4){0.f, 0.f, 0.f, 0.f};
    float z0 = 0.f, z1 = 0.f;

    for (int j0 = jbeg; j0 < jend; j0 += 64) {
#pragma unroll
        for (int s = 0; s < 2; ++s) {
            const int jj = j0 + s * 32 + hi * 8;
            const float* rp = &arT[h * NN + jj];
            f32x4 rv0 = *reinterpret_cast<const f32x4*>(rp);
            f32x4 rv1 = *reinterpret_cast<const f32x4*>(rp + 4);
            bf16x8 bX[4];
#pragma unroll
            for (int n = 0; n < 4; ++n)
                bX[n] = *reinterpret_cast<const bf16x8*>(&xlT[(h * CC + n * 16 + lo) * NN + jj]);
#pragma unroll
            for (int m = 0; m < 2; ++m) {
                const int* ap = adj + (i0 + m * 16 + lo) * NN + jj;
                i32x4 a0 = *reinterpret_cast<const i32x4*>(ap);
                i32x4 a1 = *reinterpret_cast<const i32x4*>(ap + 4);
                const float alm = m ? al1 : al0;
                float p0 = a0[0] ? __expf(alm * rv0[0]) : 0.f;
                float p1 = a0[1] ? __expf(alm * rv0[1]) : 0.f;
                float p2 = a0[2] ? __expf(alm * rv0[2]) : 0.f;
                float p3 = a0[3] ? __expf(alm * rv0[3]) : 0.f;
                float p4 = a1[0] ? __expf(alm * rv1[0]) : 0.f;
                float p5 = a1[1] ? __expf(alm * rv1[1]) : 0.f;
                float p6 = a1[2] ? __expf(alm * rv1[2]) : 0.f;
                float p7 = a1[3] ? __expf(alm * rv1[3]) : 0.f;
                float zs = ((p0 + p1) + (p2 + p3)) + ((p4 + p5) + (p6 + p7));
                if (m) z1 += zs; else z0 += zs;
                bf16x8 aP;
                aP[0] = (__bf16)p0; aP[1] = (__bf16)p1; aP[2] = (__bf16)p2; aP[3] = (__bf16)p3;
                aP[4] = (__bf16)p4; aP[5] = (__bf16)p5; aP[6] = (__bf16)p6; aP[7] = (__bf16)p7;
#pragma unroll
                for (int n = 0; n < 4; ++n)
                    acc[m][n] = __builtin_amdgcn_mfma_f32_16x16x32_bf16(aP, bX[n], acc[m][n], 0, 0, 0);
            }
        }
    }

    // Z: reduce across the 4 hi-groups (lanes sharing lo)
#pragma unroll
    for (int m = 0; m < 2; ++m) {
        float zz = m ? z1 : z0;
        zz += __shfl_xor(zz, 16);
        zz += __shfl_xor(zz, 32);
        if (hi == 0) Zp[(sp * NH + h) * NN + i0 + m * 16 + lo] = zz;
    }
    // partial accumulator store
#pragma unroll
    for (int m = 0; m < 2; ++m)
#pragma unroll
        for (int n = 0; n < 4; ++n)
#pragma unroll
            for (int r = 0; r < 4; ++r) {
                int row = i0 + m * 16 + hi * 4 + r;
                int col = h * CC + n * 16 + lo;
                Pacc[sp * (NN * HC) + row * HC + col] = acc[m][n][r];
            }
}

// ---------------- K4: combine splits, normalize, ReLU ----------------
__global__ __launch_bounds__(256) void k4_finalize(
    const float* __restrict__ Pacc, const float* __restrict__ Zp,
    float* __restrict__ out)
{
    int idx = blockIdx.x * 256 + threadIdx.x;   // 0 .. NN*HC-1
    int row = idx >> 9;
    int col = idx & 511;
    int h   = col >> 6;
    float v = Pacc[idx] + Pacc[NN * HC + idx];
    float zz = Zp[h * NN + row] + Zp[NH * NN + h * NN + row];
    float o = v / zz;
    out[idx] = o > 0.f ? o : 0.f;
}

extern "C" void kernel_launch(void* const* d_in, const int* in_sizes, int n_in,
                              void* d_out, int out_size, void* d_ws, size_t ws_size,
                              hipStream_t stream)
{
    const float* x    = (const float*)d_in[0];
    const int*   adj  = (const int*)d_in[1];
    const float* W    = (const float*)d_in[2];
    const float* bias = (const float*)d_in[3];
    const float* attl = (const float*)d_in[4];
    const float* attr = (const float*)d_in[5];
    float* out = (float*)d_out;

    char* ws = (char*)d_ws;
    __bf16* xlb = (__bf16*)(ws);                               // 4 MB
    __bf16* xlT = (__bf16*)(ws + (4u << 20));                  // 4 MB
    float*  alT = (float*)(ws + (8u << 20));                   // 128 KB
    float*  arT = (float*)(ws + (8u << 20) + (128u << 10));    // 128 KB
    float*  Zp  = (float*)(ws + (8u << 20) + (256u << 10));    // 256 KB
    float*  Pacc= (float*)(ws + (8u << 20) + (512u << 10));    // 16 MB

    k1_gemm<<<dim3(NN / 64, HC / 64), 256, 0, stream>>>(x, W, bias, xlb);
    k2_transpose_alpha<<<dim3(NN / 64, NH), 256, 0, stream>>>(xlb, attl, attr, xlT, alT, arT);
    k3_attn<<<dim3((NN / TI) * SPLITS), 512, 0, stream>>>(adj, xlT, alT, arT, Pacc, Zp);
    k4_finalize<<<dim3((NN * HC) / 256), 256, 0, stream>>>(Pacc, Zp, out);
}

// Round 2
// 124.732 us; speedup vs baseline: 1.2385x; 1.2385x over previous
//
#include <hip/hip_runtime.h>
#include <hip/hip_bf16.h>

// GATConv on MI355X.
// Pipeline:
//   K0: pack adj (64MB int32) -> 2MB bitmask (uint64 per 64 source cols)
//   K1: x_l = bf16( x @ W + b )             -> xlb [4096][512] bf16 (MFMA GEMM)
//   K2: transpose xlb -> xlT [512][4096] bf16; alpha_l/r = <x_l, att_l/r> per head
//   K3: block = (head, i-tile 32), 4 waves split j 4-ways.
//       P[i,j,h] = bit ? exp(al[i,h]*ar[j,h]) : 0  (no max-sub needed; |score|<~40)
//       acc += P @ x_l (MFMA, P built in A-frag layout, no LDS), Z += row-sums.
//       2-round LDS cross-wave reduce, then out = relu(acc/Z) written directly.

#define NN    4096
#define NF    512
#define NH    8
#define CC    64
#define HC    512   // NH*CC
#define TI    32

typedef __bf16 bf16x8 __attribute__((ext_vector_type(8)));
typedef __bf16 bf16x4 __attribute__((ext_vector_type(4)));
typedef float  f32x4  __attribute__((ext_vector_type(4)));
typedef int    i32x4  __attribute__((ext_vector_type(4)));
typedef unsigned long long u64;

// ---------------- K0: pack adjacency to bitmask ----------------
__global__ __launch_bounds__(256) void k0_pack(const int* __restrict__ adj,
                                               u64* __restrict__ bits)
{
    const int stride = gridDim.x * 256;
    for (int t = blockIdx.x * 256 + threadIdx.x; t < NN * NN; t += stride) {
        u64 m = __ballot(adj[t] != 0);
        if ((threadIdx.x & 63) == 0) bits[t >> 6] = m;
    }
}

// ---------------- K1: projection GEMM (bf16 MFMA, fp32 inputs) ----------------
__global__ __launch_bounds__(256) void k1_gemm(
    const float* __restrict__ X, const float* __restrict__ W,
    const float* __restrict__ bias, __bf16* __restrict__ xlb)
{
    __shared__ __bf16 As[64][40];
    __shared__ __bf16 BsT[64][40];

    const int tid = threadIdx.x;
    const int w  = tid >> 6;
    const int l  = tid & 63;
    const int lo = l & 15;
    const int hi = l >> 4;
    const int r0 = blockIdx.x * 64;
    const int c0 = blockIdx.y * 64;
    const int wm = (w >> 1) * 32;
    const int wn = (w & 1) * 32;

    f32x4 acc[2][2];
#pragma unroll
    for (int m = 0; m < 2; ++m)
#pragma unroll
        for (int n = 0; n < 2; ++n) acc[m][n] = (f32x4){0.f, 0.f, 0.f, 0.f};

    const int arow = tid >> 3;
    const int acol = (tid & 7) * 4;
    const int brow = tid >> 4;
    const int bcol = (tid & 15) * 4;

    for (int k0 = 0; k0 < NF; k0 += 32) {
        __syncthreads();
#pragma unroll
        for (int p = 0; p < 2; ++p) {
            int r = arow + p * 32;
            float4 v = *reinterpret_cast<const float4*>(&X[(r0 + r) * NF + k0 + acol]);
            bf16x4 av;
            av[0] = (__bf16)v.x; av[1] = (__bf16)v.y; av[2] = (__bf16)v.z; av[3] = (__bf16)v.w;
            *reinterpret_cast<bf16x4*>(&As[r][acol]) = av;
        }
#pragma unroll
        for (int p = 0; p < 2; ++p) {
            int kk = brow + p * 16;
            float4 v = *reinterpret_cast<const float4*>(&W[(k0 + kk) * HC + c0 + bcol]);
            BsT[bcol + 0][kk] = (__bf16)v.x;
            BsT[bcol + 1][kk] = (__bf16)v.y;
            BsT[bcol + 2][kk] = (__bf16)v.z;
            BsT[bcol + 3][kk] = (__bf16)v.w;
        }
        __syncthreads();

        bf16x8 a[2], b[2];
#pragma unroll
        for (int m = 0; m < 2; ++m)
            a[m] = *reinterpret_cast<const bf16x8*>(&As[wm + m * 16 + lo][hi * 8]);
#pragma unroll
        for (int n = 0; n < 2; ++n)
            b[n] = *reinterpret_cast<const bf16x8*>(&BsT[wn + n * 16 + lo][hi * 8]);
#pragma unroll
        for (int m = 0; m < 2; ++m)
#pragma unroll
            for (int n = 0; n < 2; ++n)
                acc[m][n] = __builtin_amdgcn_mfma_f32_16x16x32_bf16(a[m], b[n], acc[m][n], 0, 0, 0);
    }

#pragma unroll
    for (int m = 0; m < 2; ++m)
#pragma unroll
        for (int n = 0; n < 2; ++n) {
            int col = c0 + wn + n * 16 + lo;
            float bv = bias[col];
#pragma unroll
            for (int r = 0; r < 4; ++r) {
                int row = r0 + wm + m * 16 + hi * 4 + r;
                xlb[row * HC + col] = (__bf16)(acc[m][n][r] + bv);
            }
        }
}

// ---------------- K2: transpose + alpha ----------------
__global__ __launch_bounds__(256) void k2_transpose_alpha(
    const __bf16* __restrict__ xlb, const float* __restrict__ attl,
    const float* __restrict__ attr, __bf16* __restrict__ xlT,
    float* __restrict__ alT, float* __restrict__ arT)
{
    __shared__ __bf16 T[64][72];

    const int tid = threadIdx.x;
    const int r0 = blockIdx.x * 64;
    const int h  = blockIdx.y;
    const int c0 = h * CC;

    const int rr_  = tid >> 3;
    const int col8 = (tid & 7) * 8;

    float attl8[8], attr8[8];
#pragma unroll
    for (int j = 0; j < 8; ++j) { attl8[j] = attl[c0 + col8 + j]; attr8[j] = attr[c0 + col8 + j]; }

#pragma unroll
    for (int p = 0; p < 2; ++p) {
        int rr = rr_ + p * 32;
        bf16x8 v = *reinterpret_cast<const bf16x8*>(&xlb[(r0 + rr) * HC + c0 + col8]);
        *reinterpret_cast<bf16x8*>(&T[rr][col8]) = v;
        float pl = 0.f, pr = 0.f;
#pragma unroll
        for (int j = 0; j < 8; ++j) { float f = (float)v[j]; pl += f * attl8[j]; pr += f * attr8[j]; }
        pl += __shfl_xor(pl, 1); pl += __shfl_xor(pl, 2); pl += __shfl_xor(pl, 4);
        pr += __shfl_xor(pr, 1); pr += __shfl_xor(pr, 2); pr += __shfl_xor(pr, 4);
        if ((tid & 7) == 0) { alT[h * NN + r0 + rr] = pl; arT[h * NN + r0 + rr] = pr; }
    }
    __syncthreads();

    const int cc_  = tid >> 3;
    const int row8 = (tid & 7) * 8;
#pragma unroll
    for (int p = 0; p < 2; ++p) {
        int cc = cc_ + p * 32;
        bf16x8 g;
#pragma unroll
        for (int j = 0; j < 8; ++j) g[j] = T[row8 + j][cc];
        *reinterpret_cast<bf16x8*>(&xlT[(c0 + cc) * NN + r0 + row8]) = g;
    }
}

// ---------------- K3: fused mask+exp+aggregate+Z+normalize+ReLU ----------------
__global__ __launch_bounds__(256) void k3_attn(
    const u64* __restrict__ abits, const __bf16* __restrict__ xlT,
    const float* __restrict__ alT, const float* __restrict__ arT,
    float* __restrict__ out)
{
    __shared__ float rA[2][64][33];   // 2-round cross-wave reduction buffers
    __shared__ float rZ[2][2][16];

    const int tid = threadIdx.x;
    const int wv  = tid >> 6;        // wave 0..3 : j-split
    const int l   = tid & 63;
    const int lo  = l & 15;
    const int hi  = l >> 4;
    const int h   = blockIdx.x;      // head
    const int i0  = blockIdx.y * TI; // i-tile
    const int jbeg = wv * (NN / 4);
    const int jend = jbeg + (NN / 4);

    const float al0 = alT[h * NN + i0 + lo];
    const float al1 = alT[h * NN + i0 + 16 + lo];

    f32x4 acc[2][4];
#pragma unroll
    for (int m = 0; m < 2; ++m)
#pragma unroll
        for (int n = 0; n < 4; ++n) acc[m][n] = (f32x4){0.f, 0.f, 0.f, 0.f};
    float z0 = 0.f, z1 = 0.f;

    const u64* ab0p = &abits[(i0 + lo) * 64];
    const u64* ab1p = &abits[(i0 + 16 + lo) * 64];

    for (int j0 = jbeg; j0 < jend; j0 += 64) {
        const u64 ab0 = ab0p[j0 >> 6];
        const u64 ab1 = ab1p[j0 >> 6];
#pragma unroll
        for (int s = 0; s < 2; ++s) {
            const int jj = j0 + s * 32 + hi * 8;
            const float* rp = &arT[h * NN + jj];
            f32x4 rv0 = *reinterpret_cast<const f32x4*>(rp);
            f32x4 rv1 = *reinterpret_cast<const f32x4*>(rp + 4);
            bf16x8 bX[4];
#pragma unroll
            for (int n = 0; n < 4; ++n)
                bX[n] = *reinterpret_cast<const bf16x8*>(&xlT[(h * CC + n * 16 + lo) * NN + jj]);
            const int sh = s * 32 + hi * 8;
#pragma unroll
            for (int m = 0; m < 2; ++m) {
                const unsigned int byte = (unsigned int)(((m ? ab1 : ab0) >> sh) & 0xffULL);
                const float alm = m ? al1 : al0;
                float p0 = (byte & 1u)   ? __expf(alm * rv0[0]) : 0.f;
                float p1 = (byte & 2u)   ? __expf(alm * rv0[1]) : 0.f;
                float p2 = (byte & 4u)   ? __expf(alm * rv0[2]) : 0.f;
                float p3 = (byte & 8u)   ? __expf(alm * rv0[3]) : 0.f;
                float p4 = (byte & 16u)  ? __expf(alm * rv1[0]) : 0.f;
                float p5 = (byte & 32u)  ? __expf(alm * rv1[1]) : 0.f;
                float p6 = (byte & 64u)  ? __expf(alm * rv1[2]) : 0.f;
                float p7 = (byte & 128u) ? __expf(alm * rv1[3]) : 0.f;
                float zs = ((p0 + p1) + (p2 + p3)) + ((p4 + p5) + (p6 + p7));
                if (m) z1 += zs; else z0 += zs;
                bf16x8 aP;
                aP[0] = (__bf16)p0; aP[1] = (__bf16)p1; aP[2] = (__bf16)p2; aP[3] = (__bf16)p3;
                aP[4] = (__bf16)p4; aP[5] = (__bf16)p5; aP[6] = (__bf16)p6; aP[7] = (__bf16)p7;
#pragma unroll
                for (int n = 0; n < 4; ++n)
                    acc[m][n] = __builtin_amdgcn_mfma_f32_16x16x32_bf16(aP, bX[n], acc[m][n], 0, 0, 0);
            }
        }
    }

    // full-wave z reduce across hi groups (butterfly: every lane gets total)
    z0 += __shfl_xor(z0, 16); z0 += __shfl_xor(z0, 32);
    z1 += __shfl_xor(z1, 16); z1 += __shfl_xor(z1, 32);

    // ---- round 1: waves 2,3 -> LDS; waves 0,1 add ----
    if (wv >= 2) {
#pragma unroll
        for (int m = 0; m < 2; ++m)
#pragma unroll
            for (int n = 0; n < 4; ++n)
#pragma unroll
                for (int r = 0; r < 4; ++r)
                    rA[wv - 2][l][m * 16 + n * 4 + r] = acc[m][n][r];
        if (hi == 0) { rZ[wv - 2][0][lo] = z0; rZ[wv - 2][1][lo] = z1; }
    }
    __syncthreads();
    if (wv < 2) {
#pragma unroll
        for (int m = 0; m < 2; ++m)
#pragma unroll
            for (int n = 0; n < 4; ++n)
#pragma unroll
                for (int r = 0; r < 4; ++r)
                    acc[m][n][r] += rA[wv][l][m * 16 + n * 4 + r];
        z0 += rZ[wv][0][lo];
        z1 += rZ[wv][1][lo];
    }
    __syncthreads();
    // ---- round 2: wave 1 -> LDS slot 0; wave 0 adds, finalizes ----
    if (wv == 1) {
#pragma unroll
        for (int m = 0; m < 2; ++m)
#pragma unroll
            for (int n = 0; n < 4; ++n)
#pragma unroll
                for (int r = 0; r < 4; ++r)
                    rA[0][l][m * 16 + n * 4 + r] = acc[m][n][r];
        if (hi == 0) { rZ[0][0][lo] = z0; rZ[0][1][lo] = z1; }
    }
    __syncthreads();
    if (wv == 0) {
#pragma unroll
        for (int m = 0; m < 2; ++m)
#pragma unroll
            for (int n = 0; n < 4; ++n)
#pragma unroll
                for (int r = 0; r < 4; ++r)
                    acc[m][n][r] += rA[0][l][m * 16 + n * 4 + r];
        z0 += rZ[0][0][lo];
        z1 += rZ[0][1][lo];
        // publish final Z per row (indexed by lo) for all lanes to read by row
        if (hi == 0) { rZ[1][0][lo] = z0; rZ[1][1][lo] = z1; }
#pragma unroll
        for (int m = 0; m < 2; ++m)
#pragma unroll
            for (int n = 0; n < 4; ++n)
#pragma unroll
                for (int r = 0; r < 4; ++r) {
                    const int rr = hi * 4 + r;
                    const float zf = rZ[1][m][rr];
                    const float o = acc[m][n][r] / zf;
                    out[(i0 + m * 16 + rr) * HC + h * CC + n * 16 + lo] = o > 0.f ? o : 0.f;
                }
    }
}

extern "C" void kernel_launch(void* const* d_in, const int* in_sizes, int n_in,
                              void* d_out, int out_size, void* d_ws, size_t ws_size,
                              hipStream_t stream)
{
    const float* x    = (const float*)d_in[0];
    const int*   adj  = (const int*)d_in[1];
    const float* W    = (const float*)d_in[2];
    const float* bias = (const float*)d_in[3];
    const float* attl = (const float*)d_in[4];
    const float* attr = (const float*)d_in[5];
    float* out = (float*)d_out;

    char* ws = (char*)d_ws;
    __bf16* xlb  = (__bf16*)(ws);                               // 4 MB
    __bf16* xlT  = (__bf16*)(ws + (4u << 20));                  // 4 MB
    float*  alT  = (float*)(ws + (8u << 20));                   // 128 KB
    float*  arT  = (float*)(ws + (8u << 20) + (128u << 10));    // 128 KB
    u64*    abit = (u64*)(ws + (8u << 20) + (256u << 10));      // 2 MB

    k0_pack<<<dim3(4096), 256, 0, stream>>>(adj, abit);
    k1_gemm<<<dim3(NN / 64, HC / 64), 256, 0, stream>>>(x, W, bias, xlb);
    k2_transpose_alpha<<<dim3(NN / 64, NH), 256, 0, stream>>>(xlb, attl, attr, xlT, alT, arT);
    k3_attn<<<dim3(NH, NN / TI), 256, 0, stream>>>(abit, xlT, alT, arT, out);
}